// Round 10
// baseline (256.916 us; speedup 1.0000x reference)
//
#include <hip/hip_runtime.h>
#include <hip/hip_bf16.h>
#include <math.h>

#define SS 8
#define NN 32
#define DD 64
#define NP 496   // 32*31/2
#define LDA 68   // padded row stride (floats) for sAi/sBj; 272B (16B-aligned)

typedef short v8s __attribute__((ext_vector_type(8)));   // 8 bf16 (4 VGPRs)
typedef float v4f __attribute__((ext_vector_type(4)));   // MFMA C/D frag
typedef float f2  __attribute__((ext_vector_type(2)));   // packed fp32 pair (VOP3P)

union FragU { uint4 u; v8s s; };
union Q2    { float4 q; f2 h[2]; };

static __device__ __forceinline__ f2 f2m(float a, float b) { f2 r; r.x = a; r.y = b; return r; }
static __device__ __forceinline__ f2 splat2(float s) { f2 r; r.x = s; r.y = s; return r; }
static __device__ __forceinline__ f2 pk_fma(f2 a, f2 b, f2 c) {
#if __has_builtin(__builtin_elementwise_fma)
    return __builtin_elementwise_fma(a, b, c);    // -> v_pk_fma_f32
#else
    return f2m(fmaf(a.x, b.x, c.x), fmaf(a.y, b.y, c.y));
#endif
}

__device__ __forceinline__ float wrap_pi(float d) {
    return fmaf(-6.28318530717958647692f, rintf(d * 0.15915494309189533577f), d);
}
// sigmoid via hw rcp (avoids the ~10-inst v_div refinement chain; 1e-7 rel err)
__device__ __forceinline__ float sigmoid_(float x) {
    return __builtin_amdgcn_rcpf(1.0f + __expf(-x));
}
// Sign-free packed GELU. erf via A&S 7.1.25 (|eps|<=5e-4, no exp, 1 rcp/elem).
// Uses oddness of erf: gelu(x) = (0.5x + a) - (a*t^2)*t^2 with a = 0.5|x|,
// t = 1/P(|z|) — no sign-transfer ops. Saturates correctly for |x| up to 1e8.
__device__ __forceinline__ f2 gelu2(f2 x) {
#if __has_builtin(__builtin_elementwise_max)
    f2 ax = __builtin_elementwise_max(x, -x);
#else
    f2 ax = f2m(fabsf(x.x), fabsf(x.y));
#endif
    f2 az = ax * splat2(0.70710678118654752440f);
    f2 d = pk_fma(splat2(0.078108f), az, splat2(0.000972f));
    d = pk_fma(d, az, splat2(0.230389f));
    d = pk_fma(d, az, splat2(0.278393f));
    d = pk_fma(d, az, splat2(1.0f));
    f2 t = f2m(__builtin_amdgcn_rcpf(d.x), __builtin_amdgcn_rcpf(d.y));
    f2 t2 = t * t;
    f2 a = ax * splat2(0.5f);
    f2 base = pk_fma(x, splat2(0.5f), a);
    f2 u = a * t2;
    return pk_fma(-u, t2, base);
}
// fp32 pair -> packed bf16 (RNE). HW path: v_cvt_pk_bf16_f32 on gfx950.
__device__ __forceinline__ unsigned int pack_bf16_rne(float x0, float x1) {
    union { __hip_bfloat162 h2; unsigned int u; } cv;
    float2 f; f.x = x0; f.y = x1;
    cv.h2 = __float22bfloat162_rn(f);
    return cv.u;
}
// bf16-pair unpack halves (1 VALU inst each)
__device__ __forceinline__ float bf_lo(unsigned int u) { return __uint_as_float(u << 16); }
__device__ __forceinline__ float bf_hi(unsigned int u) { return __uint_as_float(u & 0xffff0000u); }
// Sum across each 16-lane DPP row via row_ror 8/4/2/1 (rotation butterfly:
// every lane ends with the full row sum, direction-agnostic). VALU pipe.
__device__ __forceinline__ float row_reduce16(float x) {
    int v;
    v = __builtin_amdgcn_update_dpp(0, __float_as_int(x), 0x128, 0xf, 0xf, false);
    x += __int_as_float(v);
    v = __builtin_amdgcn_update_dpp(0, __float_as_int(x), 0x124, 0xf, 0xf, false);
    x += __int_as_float(v);
    v = __builtin_amdgcn_update_dpp(0, __float_as_int(x), 0x122, 0xf, 0xf, false);
    x += __int_as_float(v);
    v = __builtin_amdgcn_update_dpp(0, __float_as_int(x), 0x121, 0xf, 0xf, false);
    x += __int_as_float(v);
    return x;
}
__device__ __forceinline__ uint4 build_w2_frag(const float* __restrict__ W2,
                                               int kb, int col) {
    uint4 pk;
    pk.x = pack_bf16_rne(W2[(kb + 0) * 32 + col], W2[(kb + 1) * 32 + col]);
    pk.y = pack_bf16_rne(W2[(kb + 2) * 32 + col], W2[(kb + 3) * 32 + col]);
    pk.z = pack_bf16_rne(W2[(kb + 4) * 32 + col], W2[(kb + 5) * 32 + col]);
    pk.w = pack_bf16_rne(W2[(kb + 6) * 32 + col], W2[(kb + 7) * 32 + col]);
    return pk;
}

__global__ __launch_bounds__(256, 2) void edge_kernel(
    const float* __restrict__ cel,    // (B,S,N,D)
    const float* __restrict__ theta,  // (B,N)
    const float* __restrict__ phi,
    const float* __restrict__ vel,
    const float* __restrict__ rad,
    const float* __restrict__ lon,
    const float* __restrict__ W1,     // (134,64)
    const float* __restrict__ b1,     // (64)
    const float* __restrict__ W2,     // (64,32)
    const float* __restrict__ b2,     // (32)
    const float* __restrict__ W3,     // (32)
    const float* __restrict__ b3,     // (1)
    const float* __restrict__ pw,     // (6)
    float* __restrict__ out)          // (B,N,N)
{
    // LDS budget <= 32768 B -> 5 blocks/CU if LDS binds occupancy:
    // 8704+8704+1536+4096+5952+1984+496+496 = 31968
    __shared__ __align__(16) float sAi[NN * LDA];     // fi@W1[0:64] + b1
    __shared__ __align__(16) float sBj[NN * LDA];     // fj@W1[64:128]
    __shared__ __align__(16) float sW1s[6 * 64];      // W1 rows 128..133
    __shared__ float sAdj[1024];
    __shared__ unsigned int sScalPk[3][NP];           // bf16 pairs (td,pd)(vd,rr)(ld,pr)
    __shared__ float sGate[NP];
    __shared__ unsigned char sI[NP], sJ[NP];

    const int b = blockIdx.x;
    const int t = threadIdx.x;
    const int ml = t & 15;            // frag row-within-tile / C col
    const int ql = (t >> 4) & 3;      // frag k-quad / C row-quad (== lane>>4)
    const int wv = t >> 6;            // wave id
    const int kA = ql * 8;            // this lane's ks0 k-base

    // ---- B-fragments of W2 straight from global (per-thread, no LDS) ----
    FragU f00, f01, f10, f11;
    f00.u = build_w2_frag(W2, 0 * 32 + kA, 0 * 16 + ml);
    f01.u = build_w2_frag(W2, 1 * 32 + kA, 0 * 16 + ml);
    f10.u = build_w2_frag(W2, 0 * 32 + kA, 1 * 16 + ml);
    f11.u = build_w2_frag(W2, 1 * 32 + kA, 1 * 16 + ml);
    const float b2v0 = b2[ml], b2v1 = b2[16 + ml];
    const float w3v0 = W3[ml], w3v1 = W3[16 + ml];
    const float b3s  = b3[0];

    // ---- staging ----
    if (t < 31) {  // triu pair table
        int off = t * 31 - (t * (t - 1)) / 2;
        for (int j = t + 1; j < 32; ++j) {
            sI[off] = (unsigned char)t;
            sJ[off] = (unsigned char)j;
            ++off;
        }
    }
    for (int idx = t; idx < 1024; idx += 256) sAdj[idx] = 0.0f;
    for (int idx = t; idx < 384; idx += 256) sW1s[idx] = W1[128 * 64 + idx];
    __syncthreads();   // barrier 1

    // ---- per-pair scalars + gate (node attrs read straight from global;
    //      tiny, L1-broadcast — no LDS staging needed) ----
    for (int p = t; p < NP; p += 256) {
        const int i = sI[p], j = sJ[p];
        const float td = wrap_pi(theta[b * NN + i] - theta[b * NN + j]);
        const float pd = wrap_pi(phi[b * NN + i] - phi[b * NN + j]);
        const float vd = vel[b * NN + i] - vel[b * NN + j];
        const float rr = rad[b * NN + i] * __builtin_amdgcn_rcpf(rad[b * NN + j] + 1e-8f);
        const float ld = wrap_pi(lon[b * NN + i] - lon[b * NN + j]);
        const float pr = __cosf(td) * __cosf(pd);
        sScalPk[0][p] = pack_bf16_rne(td, pd);
        sScalPk[1][p] = pack_bf16_rne(vd, rr);
        sScalPk[2][p] = pack_bf16_rne(ld, pr);
        const float pf = fabsf(td) * pw[0] + fabsf(pd) * pw[1]
                       + fabsf(vd) * pw[2] + fabsf(rr - 1.0f) * pw[3]
                       + fabsf(ld) * pw[4] + fabsf(pr) * pw[5];
        sGate[p] = sigmoid_(pf);
    }

    // ---- phase A: node projections (packed fp32 VALU) ----
    {
        const int col = t & 63;
        const int w   = __builtin_amdgcn_readfirstlane(t >> 6);
        const float* fbase = cel + ((size_t)b * SS + (SS - 1)) * (NN * DD);
        f2 accA[8], accB[8];
        #pragma unroll
        for (int m = 0; m < 8; ++m) { accA[m] = splat2(0.0f); accB[m] = splat2(0.0f); }
        for (int k4 = 0; k4 < 64; k4 += 4) {
            const f2 wa01 = f2m(W1[(k4 + 0) * 64 + col], W1[(k4 + 1) * 64 + col]);
            const f2 wa23 = f2m(W1[(k4 + 2) * 64 + col], W1[(k4 + 3) * 64 + col]);
            const f2 wb01 = f2m(W1[(k4 + 64) * 64 + col], W1[(k4 + 65) * 64 + col]);
            const f2 wb23 = f2m(W1[(k4 + 66) * 64 + col], W1[(k4 + 67) * 64 + col]);
            #pragma unroll
            for (int m = 0; m < 8; ++m) {
                const float4 fv = *(const float4*)&fbase[(w + 4 * m) * 64 + k4]; // s_load_dwordx4
                accA[m] = pk_fma(f2m(fv.x, fv.y), wa01, accA[m]);
                accA[m] = pk_fma(f2m(fv.z, fv.w), wa23, accA[m]);
                accB[m] = pk_fma(f2m(fv.x, fv.y), wb01, accB[m]);
                accB[m] = pk_fma(f2m(fv.z, fv.w), wb23, accB[m]);
            }
        }
        const float b1c = b1[col];
        #pragma unroll
        for (int m = 0; m < 8; ++m) {
            sAi[(w + 4 * m) * LDA + col] = accA[m].x + accA[m].y + b1c;
            sBj[(w + 4 * m) * LDA + col] = accB[m].x + accB[m].y;
        }
    }
    __syncthreads();   // barrier 2

    // ---- hoist this lane's ks0 slice of W1s (48 regs; registers are NOT the
    //      occupancy binder — R8 vs R9 both ran ~3 blocks/CU at 64 vs 52 VGPR) ----
    f2 w1f[6][4];
    #pragma unroll
    for (int s = 0; s < 6; ++s) {
        Q2 u0, u1;
        u0.q = *(const float4*)&sW1s[s * 64 + kA];
        u1.q = *(const float4*)&sW1s[s * 64 + kA + 4];
        w1f[s][0] = u0.h[0]; w1f[s][1] = u0.h[1];
        w1f[s][2] = u1.h[0]; w1f[s][3] = u1.h[1];
    }

    // ---- main loop: one 16-pair m-tile per wave-round, ZERO barriers ----
    #pragma clang loop unroll(disable)
    for (int r = 0; r < 8; ++r) {
        const int mtl = r * 4 + wv;
        if (mtl >= 31) break;                    // wave-uniform
        const int p = mtl * 16 + ml;
        const int i = sI[p], j = sJ[p];
        const unsigned int u0 = sScalPk[0][p];
        const unsigned int u1 = sScalPk[1][p];
        const unsigned int u2 = sScalPk[2][p];
        float sc[6] = {bf_lo(u0), bf_hi(u0), bf_lo(u1), bf_hi(u1), bf_lo(u2), bf_hi(u2)};
        const float* Ar = &sAi[i * LDA];
        const float* Br = &sBj[j * LDA];

        // ks0 half: k = kA..kA+7 (W1s slice from registers)
        FragU fa0, fa1;
        {
            Q2 P0, P1, Q0, Q1;
            P0.q = *(const float4*)(Ar + kA);
            P1.q = *(const float4*)(Ar + kA + 4);
            Q0.q = *(const float4*)(Br + kA);
            Q1.q = *(const float4*)(Br + kA + 4);
            f2 v[4] = {P0.h[0] + Q0.h[0], P0.h[1] + Q0.h[1],
                       P1.h[0] + Q1.h[0], P1.h[1] + Q1.h[1]};
            #pragma unroll
            for (int s = 0; s < 6; ++s) {
                const f2 scs = splat2(sc[s]);
                #pragma unroll
                for (int c = 0; c < 4; ++c)
                    v[c] = pk_fma(scs, w1f[s][c], v[c]);
            }
            #pragma unroll
            for (int c = 0; c < 4; ++c) v[c] = gelu2(v[c]);
            fa0.u.x = pack_bf16_rne(v[0].x, v[0].y);
            fa0.u.y = pack_bf16_rne(v[1].x, v[1].y);
            fa0.u.z = pack_bf16_rne(v[2].x, v[2].y);
            fa0.u.w = pack_bf16_rne(v[3].x, v[3].y);
        }
        // ks1 half: k = 32+kA.. (W1s slice streamed from LDS)
        {
            Q2 P2, P3, Q2v, Q3;
            P2.q  = *(const float4*)(Ar + 32 + kA);
            P3.q  = *(const float4*)(Ar + 36 + kA);
            Q2v.q = *(const float4*)(Br + 32 + kA);
            Q3.q  = *(const float4*)(Br + 36 + kA);
            f2 y[4] = {P2.h[0] + Q2v.h[0], P2.h[1] + Q2v.h[1],
                       P3.h[0] + Q3.h[0],  P3.h[1] + Q3.h[1]};
            #pragma unroll
            for (int s = 0; s < 6; ++s) {
                const f2 scs = splat2(sc[s]);
                Q2 W0, W1v;
                W0.q  = *(const float4*)&sW1s[s * 64 + 32 + kA];
                W1v.q = *(const float4*)&sW1s[s * 64 + 36 + kA];
                y[0] = pk_fma(scs, W0.h[0],  y[0]);
                y[1] = pk_fma(scs, W0.h[1],  y[1]);
                y[2] = pk_fma(scs, W1v.h[0], y[2]);
                y[3] = pk_fma(scs, W1v.h[1], y[3]);
            }
            #pragma unroll
            for (int c = 0; c < 4; ++c) y[c] = gelu2(y[c]);
            fa1.u.x = pack_bf16_rne(y[0].x, y[0].y);
            fa1.u.y = pack_bf16_rne(y[1].x, y[1].y);
            fa1.u.z = pack_bf16_rne(y[2].x, y[2].y);
            fa1.u.w = pack_bf16_rne(y[3].x, y[3].y);
        }

        // h2 = h1 @ W2 on the matrix pipe
        v4f acc0 = {b2v0, b2v0, b2v0, b2v0};
        v4f acc1 = {b2v1, b2v1, b2v1, b2v1};
        acc0 = __builtin_amdgcn_mfma_f32_16x16x32_bf16(fa0.s, f00.s, acc0, 0, 0, 0);
        acc0 = __builtin_amdgcn_mfma_f32_16x16x32_bf16(fa1.s, f01.s, acc0, 0, 0, 0);
        acc1 = __builtin_amdgcn_mfma_f32_16x16x32_bf16(fa0.s, f10.s, acc1, 0, 0, 0);
        acc1 = __builtin_amdgcn_mfma_f32_16x16x32_bf16(fa1.s, f11.s, acc1, 0, 0, 0);

        // epilogue: pk gelu + W3 dot (row_ror reduce leaves sum in EVERY lane)
        // -> lane rsel=ml&3 picks its pair -> ONE sigmoid/gate per tile.
        float cres[4];
        #pragma unroll
        for (int rr = 0; rr < 4; ++rr) {
            const f2 g = gelu2(f2m(acc0[rr], acc1[rr]));
            cres[rr] = row_reduce16(fmaf(g.y, w3v1, g.x * w3v0));
        }
        const int rsel = ml & 3;     // constant-index ternary: no scratch
        const float cs = (rsel & 2) ? ((rsel & 1) ? cres[3] : cres[2])
                                    : ((rsel & 1) ? cres[1] : cres[0]);
        const int pe = mtl * 16 + ql * 4 + rsel;
        const float fe = sigmoid_(cs + b3s) * sGate[pe];
        if (ml < 4) {
            const int pi = sI[pe], pj = sJ[pe];
            sAdj[pi * 32 + pj] = fe;
            sAdj[pj * 32 + pi] = fe;
        }
    }
    __syncthreads();   // barrier 3

    // ---- coalesced tile writeback ----
    float* dst = out + (size_t)b * 1024;
    for (int idx = t; idx < 1024; idx += 256) dst[idx] = sAdj[idx];
}

extern "C" void kernel_launch(void* const* d_in, const int* in_sizes, int n_in,
                              void* d_out, int out_size, void* d_ws, size_t ws_size,
                              hipStream_t stream) {
    const float* cel   = (const float*)d_in[0];
    const float* theta = (const float*)d_in[1];
    const float* phi   = (const float*)d_in[2];
    const float* vel   = (const float*)d_in[3];
    const float* rad   = (const float*)d_in[4];
    const float* lon   = (const float*)d_in[5];
    const float* W1    = (const float*)d_in[6];
    const float* b1    = (const float*)d_in[7];
    const float* W2    = (const float*)d_in[8];
    const float* b2    = (const float*)d_in[9];
    const float* W3    = (const float*)d_in[10];
    const float* b3    = (const float*)d_in[11];
    const float* pw    = (const float*)d_in[12];
    float* out = (float*)d_out;

    const int B = in_sizes[1] / NN;  // theta is (B,N)
    edge_kernel<<<B, 256, 0, stream>>>(cel, theta, phi, vel, rad, lon,
                                       W1, b1, W2, b2, W3, b3, pw, out);
}

// Round 11
// 256.140 us; speedup vs baseline: 1.0030x; 1.0030x over previous
//
#include <hip/hip_runtime.h>
#include <hip/hip_bf16.h>
#include <math.h>

#define SS 8
#define NN 32
#define DD 64
#define NP 496   // 32*31/2
#define LDA 68   // padded row stride (floats) for sAi/sBj; 272B (16B-aligned)

typedef short v8s __attribute__((ext_vector_type(8)));   // 8 bf16 (4 VGPRs)
typedef float v4f __attribute__((ext_vector_type(4)));   // MFMA C/D frag
typedef float f2  __attribute__((ext_vector_type(2)));   // packed fp32 pair (VOP3P)

union FragU { uint4 u; v8s s; };
union Q2    { float4 q; f2 h[2]; };

static __device__ __forceinline__ f2 f2m(float a, float b) { f2 r; r.x = a; r.y = b; return r; }
static __device__ __forceinline__ f2 splat2(float s) { f2 r; r.x = s; r.y = s; return r; }
static __device__ __forceinline__ f2 pk_fma(f2 a, f2 b, f2 c) {
#if __has_builtin(__builtin_elementwise_fma)
    return __builtin_elementwise_fma(a, b, c);    // -> v_pk_fma_f32
#else
    return f2m(fmaf(a.x, b.x, c.x), fmaf(a.y, b.y, c.y));
#endif
}

__device__ __forceinline__ float wrap_pi(float d) {
    return fmaf(-6.28318530717958647692f, rintf(d * 0.15915494309189533577f), d);
}
// sigmoid via hw rcp (avoids the ~10-inst v_div refinement chain; 1e-7 rel err)
__device__ __forceinline__ float sigmoid_(float x) {
    return __builtin_amdgcn_rcpf(1.0f + __expf(-x));
}
// Sign-free packed GELU. erf via A&S 7.1.25-style rational (|eps|<=5e-4, no
// exp, 1 rcp/elem). gelu(x) = (0.5x + a) - (a*t^2)*t^2, a = 0.5|x|.
__device__ __forceinline__ f2 gelu2(f2 x) {
#if __has_builtin(__builtin_elementwise_max)
    f2 ax = __builtin_elementwise_max(x, -x);
#else
    f2 ax = f2m(fabsf(x.x), fabsf(x.y));
#endif
    f2 az = ax * splat2(0.70710678118654752440f);
    f2 d = pk_fma(splat2(0.078108f), az, splat2(0.000972f));
    d = pk_fma(d, az, splat2(0.230389f));
    d = pk_fma(d, az, splat2(0.278393f));
    d = pk_fma(d, az, splat2(1.0f));
    f2 t = f2m(__builtin_amdgcn_rcpf(d.x), __builtin_amdgcn_rcpf(d.y));
    f2 t2 = t * t;
    f2 a = ax * splat2(0.5f);
    f2 base = pk_fma(x, splat2(0.5f), a);
    f2 u = a * t2;
    return pk_fma(-u, t2, base);
}
// fp32 pair -> packed bf16 (RNE). HW path: v_cvt_pk_bf16_f32 on gfx950.
__device__ __forceinline__ unsigned int pack_bf16_rne(float x0, float x1) {
    union { __hip_bfloat162 h2; unsigned int u; } cv;
    float2 f; f.x = x0; f.y = x1;
    cv.h2 = __float22bfloat162_rn(f);
    return cv.u;
}
// Sum across each 16-lane DPP row via row_ror 8/4/2/1 (rotation butterfly:
// every lane ends with the full row sum, direction-agnostic). VALU pipe.
__device__ __forceinline__ float row_reduce16(float x) {
    int v;
    v = __builtin_amdgcn_update_dpp(0, __float_as_int(x), 0x128, 0xf, 0xf, false);
    x += __int_as_float(v);
    v = __builtin_amdgcn_update_dpp(0, __float_as_int(x), 0x124, 0xf, 0xf, false);
    x += __int_as_float(v);
    v = __builtin_amdgcn_update_dpp(0, __float_as_int(x), 0x122, 0xf, 0xf, false);
    x += __int_as_float(v);
    v = __builtin_amdgcn_update_dpp(0, __float_as_int(x), 0x121, 0xf, 0xf, false);
    x += __int_as_float(v);
    return x;
}
__device__ __forceinline__ uint4 build_w2_frag(const float* __restrict__ W2,
                                               int kb, int col) {
    uint4 pk;
    pk.x = pack_bf16_rne(W2[(kb + 0) * 32 + col], W2[(kb + 1) * 32 + col]);
    pk.y = pack_bf16_rne(W2[(kb + 2) * 32 + col], W2[(kb + 3) * 32 + col]);
    pk.z = pack_bf16_rne(W2[(kb + 4) * 32 + col], W2[(kb + 5) * 32 + col]);
    pk.w = pack_bf16_rne(W2[(kb + 6) * 32 + col], W2[(kb + 7) * 32 + col]);
    return pk;
}

__global__ __launch_bounds__(256, 2) void edge_kernel(
    const float* __restrict__ cel,    // (B,S,N,D)
    const float* __restrict__ theta,  // (B,N)
    const float* __restrict__ phi,
    const float* __restrict__ vel,
    const float* __restrict__ rad,
    const float* __restrict__ lon,
    const float* __restrict__ W1,     // (134,64)
    const float* __restrict__ b1,     // (64)
    const float* __restrict__ W2,     // (64,32)
    const float* __restrict__ b2,     // (32)
    const float* __restrict__ W3,     // (32)
    const float* __restrict__ b3,     // (1)
    const float* __restrict__ pw,     // (6)
    float* __restrict__ out)          // (B,N,N)
{
    // LDS ~41.9 KB -> 3 blocks/CU (R9/R10 proved 32-39 KB all land at 3; size
    // is not the occupancy binder, so spend LDS where it cuts instructions).
    __shared__ __align__(16) float sAi[NN * LDA];     // fi@W1[0:64] + b1
    __shared__ __align__(16) float sBj[NN * LDA];     // fj@W1[64:128]
    __shared__ __align__(16) float sW1s[6 * 64];      // W1 rows 128..133
    __shared__ float sAdj[1024];
    __shared__ __align__(16) float sScal[NP * 8];     // f32, stride 8 -> 2 b128/pair
    __shared__ float sGate[NP];
    __shared__ unsigned char sI[NP], sJ[NP];

    const int b = blockIdx.x;
    const int t = threadIdx.x;
    const int ml = t & 15;            // frag row-within-tile / C col
    const int ql = (t >> 4) & 3;      // frag k-quad / C row-quad (== lane>>4)
    const int wv = t >> 6;            // wave id
    const int kA = ql * 8;            // this lane's ks0 k-base

    // ---- B-fragments of W2 straight from global (per-thread, no LDS) ----
    FragU f00, f01, f10, f11;
    f00.u = build_w2_frag(W2, 0 * 32 + kA, 0 * 16 + ml);
    f01.u = build_w2_frag(W2, 1 * 32 + kA, 0 * 16 + ml);
    f10.u = build_w2_frag(W2, 0 * 32 + kA, 1 * 16 + ml);
    f11.u = build_w2_frag(W2, 1 * 32 + kA, 1 * 16 + ml);
    const float b2v0 = b2[ml], b2v1 = b2[16 + ml];
    const float w3v0 = W3[ml], w3v1 = W3[16 + ml];
    const float b3s  = b3[0];

    // ---- staging ----
    if (t < 31) {  // triu pair table
        int off = t * 31 - (t * (t - 1)) / 2;
        for (int j = t + 1; j < 32; ++j) {
            sI[off] = (unsigned char)t;
            sJ[off] = (unsigned char)j;
            ++off;
        }
    }
    for (int idx = t; idx < 1024; idx += 256) sAdj[idx] = 0.0f;
    for (int idx = t; idx < 384; idx += 256) sW1s[idx] = W1[128 * 64 + idx];
    __syncthreads();   // barrier 1

    // ---- per-pair scalars + gate (node attrs straight from global: tiny,
    //      L1-broadcast) ----
    for (int p = t; p < NP; p += 256) {
        const int i = sI[p], j = sJ[p];
        const float td = wrap_pi(theta[b * NN + i] - theta[b * NN + j]);
        const float pd = wrap_pi(phi[b * NN + i] - phi[b * NN + j]);
        const float vd = vel[b * NN + i] - vel[b * NN + j];
        const float rr = rad[b * NN + i] * __builtin_amdgcn_rcpf(rad[b * NN + j] + 1e-8f);
        const float ld = wrap_pi(lon[b * NN + i] - lon[b * NN + j]);
        const float pr = __cosf(td) * __cosf(pd);
        sScal[p * 8 + 0] = td; sScal[p * 8 + 1] = pd;
        sScal[p * 8 + 2] = vd; sScal[p * 8 + 3] = rr;
        sScal[p * 8 + 4] = ld; sScal[p * 8 + 5] = pr;
        const float pf = fabsf(td) * pw[0] + fabsf(pd) * pw[1]
                       + fabsf(vd) * pw[2] + fabsf(rr - 1.0f) * pw[3]
                       + fabsf(ld) * pw[4] + fabsf(pr) * pw[5];
        sGate[p] = sigmoid_(pf);
    }

    // ---- phase A: node projections (packed fp32 VALU) ----
    {
        const int col = t & 63;
        const int w   = __builtin_amdgcn_readfirstlane(t >> 6);
        const float* fbase = cel + ((size_t)b * SS + (SS - 1)) * (NN * DD);
        f2 accA[8], accB[8];
        #pragma unroll
        for (int m = 0; m < 8; ++m) { accA[m] = splat2(0.0f); accB[m] = splat2(0.0f); }
        for (int k4 = 0; k4 < 64; k4 += 4) {
            const f2 wa01 = f2m(W1[(k4 + 0) * 64 + col], W1[(k4 + 1) * 64 + col]);
            const f2 wa23 = f2m(W1[(k4 + 2) * 64 + col], W1[(k4 + 3) * 64 + col]);
            const f2 wb01 = f2m(W1[(k4 + 64) * 64 + col], W1[(k4 + 65) * 64 + col]);
            const f2 wb23 = f2m(W1[(k4 + 66) * 64 + col], W1[(k4 + 67) * 64 + col]);
            #pragma unroll
            for (int m = 0; m < 8; ++m) {
                const float4 fv = *(const float4*)&fbase[(w + 4 * m) * 64 + k4]; // s_load_dwordx4
                accA[m] = pk_fma(f2m(fv.x, fv.y), wa01, accA[m]);
                accA[m] = pk_fma(f2m(fv.z, fv.w), wa23, accA[m]);
                accB[m] = pk_fma(f2m(fv.x, fv.y), wb01, accB[m]);
                accB[m] = pk_fma(f2m(fv.z, fv.w), wb23, accB[m]);
            }
        }
        const float b1c = b1[col];
        #pragma unroll
        for (int m = 0; m < 8; ++m) {
            sAi[(w + 4 * m) * LDA + col] = accA[m].x + accA[m].y + b1c;
            sBj[(w + 4 * m) * LDA + col] = accB[m].x + accB[m].y;
        }
    }
    __syncthreads();   // barrier 2

    // ---- hoist BOTH W1s halves for this lane (96 regs, round-invariant).
    // R9/R10 falsified the register-occupancy theory (52 vs 64 VGPR, 39 vs 32
    // KB LDS: occupancy pinned at ~3 blocks/CU either way) — so spend regs to
    // remove 12 identical-address ds_read_b128 from EVERY round.
    f2 w1f[6][8];
    #pragma unroll
    for (int s = 0; s < 6; ++s) {
        Q2 u0, u1, u2, u3;
        u0.q = *(const float4*)&sW1s[s * 64 + kA];
        u1.q = *(const float4*)&sW1s[s * 64 + kA + 4];
        u2.q = *(const float4*)&sW1s[s * 64 + 32 + kA];
        u3.q = *(const float4*)&sW1s[s * 64 + 36 + kA];
        w1f[s][0] = u0.h[0]; w1f[s][1] = u0.h[1];
        w1f[s][2] = u1.h[0]; w1f[s][3] = u1.h[1];
        w1f[s][4] = u2.h[0]; w1f[s][5] = u2.h[1];
        w1f[s][6] = u3.h[0]; w1f[s][7] = u3.h[1];
    }

    // ---- main loop: one 16-pair m-tile per wave-round, ZERO barriers ----
    #pragma clang loop unroll(disable)
    for (int r = 0; r < 8; ++r) {
        const int mtl = r * 4 + wv;
        if (mtl >= 31) break;                    // wave-uniform
        const int p = mtl * 16 + ml;
        const int i = sI[p], j = sJ[p];
        Q2 S0, S1;
        S0.q = *(const float4*)&sScal[p * 8];      // td,pd,vd,rr
        S1.q = *(const float4*)&sScal[p * 8 + 4];  // ld,pr,-,-
        const float sc[6] = {S0.q.x, S0.q.y, S0.q.z, S0.q.w, S1.q.x, S1.q.y};
        const float* Ar = &sAi[i * LDA];
        const float* Br = &sBj[j * LDA];

        // ks0 half: k = kA..kA+7 (W1s from registers)
        FragU fa0, fa1;
        {
            Q2 P0, P1, Q0, Q1;
            P0.q = *(const float4*)(Ar + kA);
            P1.q = *(const float4*)(Ar + kA + 4);
            Q0.q = *(const float4*)(Br + kA);
            Q1.q = *(const float4*)(Br + kA + 4);
            f2 v[4] = {P0.h[0] + Q0.h[0], P0.h[1] + Q0.h[1],
                       P1.h[0] + Q1.h[0], P1.h[1] + Q1.h[1]};
            #pragma unroll
            for (int s = 0; s < 6; ++s) {
                const f2 scs = splat2(sc[s]);
                #pragma unroll
                for (int c = 0; c < 4; ++c)
                    v[c] = pk_fma(scs, w1f[s][c], v[c]);
            }
            #pragma unroll
            for (int c = 0; c < 4; ++c) v[c] = gelu2(v[c]);
            fa0.u.x = pack_bf16_rne(v[0].x, v[0].y);
            fa0.u.y = pack_bf16_rne(v[1].x, v[1].y);
            fa0.u.z = pack_bf16_rne(v[2].x, v[2].y);
            fa0.u.w = pack_bf16_rne(v[3].x, v[3].y);
        }
        // ks1 half: k = 32+kA.. (W1s from registers)
        {
            Q2 P2, P3, Q2v, Q3;
            P2.q  = *(const float4*)(Ar + 32 + kA);
            P3.q  = *(const float4*)(Ar + 36 + kA);
            Q2v.q = *(const float4*)(Br + 32 + kA);
            Q3.q  = *(const float4*)(Br + 36 + kA);
            f2 y[4] = {P2.h[0] + Q2v.h[0], P2.h[1] + Q2v.h[1],
                       P3.h[0] + Q3.h[0],  P3.h[1] + Q3.h[1]};
            #pragma unroll
            for (int s = 0; s < 6; ++s) {
                const f2 scs = splat2(sc[s]);
                #pragma unroll
                for (int c = 0; c < 4; ++c)
                    y[c] = pk_fma(scs, w1f[s][4 + c], y[c]);
            }
            #pragma unroll
            for (int c = 0; c < 4; ++c) y[c] = gelu2(y[c]);
            fa1.u.x = pack_bf16_rne(y[0].x, y[0].y);
            fa1.u.y = pack_bf16_rne(y[1].x, y[1].y);
            fa1.u.z = pack_bf16_rne(y[2].x, y[2].y);
            fa1.u.w = pack_bf16_rne(y[3].x, y[3].y);
        }

        // h2 = h1 @ W2 on the matrix pipe
        v4f acc0 = {b2v0, b2v0, b2v0, b2v0};
        v4f acc1 = {b2v1, b2v1, b2v1, b2v1};
        acc0 = __builtin_amdgcn_mfma_f32_16x16x32_bf16(fa0.s, f00.s, acc0, 0, 0, 0);
        acc0 = __builtin_amdgcn_mfma_f32_16x16x32_bf16(fa1.s, f01.s, acc0, 0, 0, 0);
        acc1 = __builtin_amdgcn_mfma_f32_16x16x32_bf16(fa0.s, f10.s, acc1, 0, 0, 0);
        acc1 = __builtin_amdgcn_mfma_f32_16x16x32_bf16(fa1.s, f11.s, acc1, 0, 0, 0);

        // epilogue: pk gelu + W3 dot (row_ror reduce leaves sum in EVERY lane)
        // -> lane rsel=ml&3 picks its pair -> ONE sigmoid/gate per tile.
        float cres[4];
        #pragma unroll
        for (int rr = 0; rr < 4; ++rr) {
            const f2 g = gelu2(f2m(acc0[rr], acc1[rr]));
            cres[rr] = row_reduce16(fmaf(g.y, w3v1, g.x * w3v0));
        }
        const int rsel = ml & 3;     // constant-index ternary: no scratch
        const float cs = (rsel & 2) ? ((rsel & 1) ? cres[3] : cres[2])
                                    : ((rsel & 1) ? cres[1] : cres[0]);
        const int pe = mtl * 16 + ql * 4 + rsel;
        const float fe = sigmoid_(cs + b3s) * sGate[pe];
        if (ml < 4) {
            const int pi = sI[pe], pj = sJ[pe];
            sAdj[pi * 32 + pj] = fe;
            sAdj[pj * 32 + pi] = fe;
        }
    }
    __syncthreads();   // barrier 3

    // ---- coalesced tile writeback ----
    float* dst = out + (size_t)b * 1024;
    for (int idx = t; idx < 1024; idx += 256) dst[idx] = sAdj[idx];
}

extern "C" void kernel_launch(void* const* d_in, const int* in_sizes, int n_in,
                              void* d_out, int out_size, void* d_ws, size_t ws_size,
                              hipStream_t stream) {
    const float* cel   = (const float*)d_in[0];
    const float* theta = (const float*)d_in[1];
    const float* phi   = (const float*)d_in[2];
    const float* vel   = (const float*)d_in[3];
    const float* rad   = (const float*)d_in[4];
    const float* lon   = (const float*)d_in[5];
    const float* W1    = (const float*)d_in[6];
    const float* b1    = (const float*)d_in[7];
    const float* W2    = (const float*)d_in[8];
    const float* b2    = (const float*)d_in[9];
    const float* W3    = (const float*)d_in[10];
    const float* b3    = (const float*)d_in[11];
    const float* pw    = (const float*)d_in[12];
    float* out = (float*)d_out;

    const int B = in_sizes[1] / NN;  // theta is (B,N)
    edge_kernel<<<B, 256, 0, stream>>>(cel, theta, phi, vel, rad, lon,
                                       W1, b1, W2, b2, W3, b3, pw, out);
}